// Round 16
// baseline (4210.917 us; speedup 1.0000x reference)
//
#include <hip/hip_runtime.h>
#include <hip/hip_bf16.h>
#include <cmath>

// Problem dims
#define Bb 128
#define Tt 512
#define Ii 512
#define Hh 2048
#define Oo 512
#define REC_GRID 256

typedef __bf16 bf16_t;
typedef __bf16 bf16x8 __attribute__((ext_vector_type(8)));
typedef __bf16 bf16x4 __attribute__((ext_vector_type(4)));
typedef float  f32x4_t __attribute__((ext_vector_type(4)));
typedef unsigned u32;

static __device__ __forceinline__ bf16_t to_b(float v){ return (bf16_t)v; }
static __device__ __forceinline__ float  b2f(unsigned short u){ unsigned x = ((unsigned)u)<<16; return __builtin_bit_cast(float, x); }
static __device__ __forceinline__ unsigned short f2bbits(float v){ return __builtin_bit_cast(unsigned short, to_b(v)); }

// async global->LDS, 16B per lane: LDS dest = uniform base + lane*16, global
// source is PER-LANE (T21/m173) -- fragment-order landing via source scatter.
static __device__ __forceinline__ void gl_lds16(const void* g, void* l){
  __builtin_amdgcn_global_load_lds((const __attribute__((address_space(1))) void*)g,
                                   (__attribute__((address_space(3))) void*)l, 16, 0, 0);
}

#define REP8(M) M(0)M(1)M(2)M(3)M(4)M(5)M(6)M(7)

// ---------- small prep kernels ----------
__global__ __launch_bounds__(256) void k_f2b(bf16_t* __restrict__ dst, const float* __restrict__ src){
  size_t i = ((size_t)blockIdx.x*256 + threadIdx.x)*4;
  float4 v = *(const float4*)(src + i);
  bf16x4 o; o[0]=to_b(v.x); o[1]=to_b(v.y); o[2]=to_b(v.z); o[3]=to_b(v.w);
  *(bf16x4*)(dst + i) = o;
}

__global__ __launch_bounds__(256) void k_init_h0(const float* __restrict__ hi_w, const float* __restrict__ hi_b,
                                                 bf16_t* __restrict__ h0b){
  int i = blockIdx.x*256 + threadIdx.x;           // [0, H)
  bf16_t vb = to_b(hi_w[i] + hi_b[i]);
  for (int b=0;b<Bb;++b) h0b[(size_t)b*Hh + i] = vb;
}

__global__ __launch_bounds__(256) void k_convert_x(const float* __restrict__ x, bf16_t* __restrict__ x_tm){
  size_t idx = ((size_t)blockIdx.x*256 + threadIdx.x)*8;
  int    i0  = (int)(idx % Ii);
  size_t m   = idx / Ii;                          // m = t*B + b
  int    t   = (int)(m / Bb), b = (int)(m % Bb);
  const float* s = x + ((size_t)b*Tt + t)*Ii + i0;
  float4 v0 = *(const float4*)s, v1 = *(const float4*)(s+4);
  bf16x8 o;
  o[0]=to_b(v0.x); o[1]=to_b(v0.y); o[2]=to_b(v0.z); o[3]=to_b(v0.w);
  o[4]=to_b(v1.x); o[5]=to_b(v1.y); o[6]=to_b(v1.z); o[7]=to_b(v1.w);
  *(bf16x8*)(x_tm + idx) = o;
}

// ---------- GEMM building blocks (encoder / decoder) ----------
template<int ROWS, int KB>
static __device__ __forceinline__ void stage(const bf16_t* __restrict__ g, long ld, long row0, int k0,
                                             char* __restrict__ ldsT){
  constexpr int SLOTS = KB/8;
  constexpr int PT    = ROWS*SLOTS/256;
  #pragma unroll
  for (int j=0;j<PT;++j){
    int c    = threadIdx.x + 256*j;
    int row  = c / SLOTS, slot = c % SLOTS;
    uint4 v  = *(const uint4*)(g + (row0+row)*ld + k0 + slot*8);
    *(uint4*)(ldsT + row*(KB*2) + ((slot*16) ^ ((row&7)<<4))) = v;
  }
}

template<int KB>
static __device__ __forceinline__ bf16x8 frag(const char* __restrict__ ldsT, int row, int kk, int lane){
  int kbyte = kk*64 + ((lane>>4)<<4);
  return *(const bf16x8*)(ldsT + row*(KB*2) + (kbyte ^ ((row&7)<<4)));
}

template<int EPI>
__global__ __launch_bounds__(256) void gemm128(const bf16_t* __restrict__ A, long lda,
                                               const bf16_t* __restrict__ Bw, long ldb,
                                               const float* __restrict__ bias,
                                               void* __restrict__ Cout, long ldc, int K){
  constexpr int TM=128, TN=128, KB=64;
  __shared__ char lds[(TM+TN)*KB*2];
  char* ldsA = lds;
  char* ldsB = lds + TM*KB*2;
  long m0 = (long)blockIdx.x * TM;
  long n0 = (long)blockIdx.y * TN;
  int w = threadIdx.x >> 6, lane = threadIdx.x & 63;
  int wm = w >> 1, wn = w & 1;
  f32x4_t acc[4][4] = {};
  for (int k0=0;k0<K;k0+=KB){
    __syncthreads();
    stage<TM,KB>(A,  lda, m0, k0, ldsA);
    stage<TN,KB>(Bw, ldb, n0, k0, ldsB);
    __syncthreads();
    #pragma unroll
    for (int kk=0;kk<KB/32;++kk){
      bf16x8 af[4], bfv[4];
      #pragma unroll
      for (int f=0;f<4;++f){ int r = wm*64 + f*16 + (lane&15); af[f]  = frag<KB>(ldsA, r, kk, lane); }
      #pragma unroll
      for (int f=0;f<4;++f){ int r = wn*64 + f*16 + (lane&15); bfv[f] = frag<KB>(ldsB, r, kk, lane); }
      #pragma unroll
      for (int i=0;i<4;++i)
        #pragma unroll
        for (int j=0;j<4;++j)
          acc[i][j] = __builtin_amdgcn_mfma_f32_16x16x32_bf16(af[i], bfv[j], acc[i][j], 0,0,0);
    }
  }
  #pragma unroll
  for (int i=0;i<4;++i)
    #pragma unroll
    for (int j=0;j<4;++j)
      #pragma unroll
      for (int e=0;e<4;++e){
        long row = m0 + wm*64 + i*16 + ((lane>>4)<<2) + e;
        long col = n0 + wn*64 + j*16 + (lane&15);
        float v = acc[i][j][e] + bias[col];
        if (EPI==0) ((bf16_t*)Cout)[row*ldc + col] = to_b(v);
        else        ((float*) Cout)[row*ldc + col] = v;
      }
}

// ---------- persistent recurrence kernel (1024 threads / 16 waves) ----------
// Two-phase pipelined recurrence (R15 schedule, alias bug fixed):
// 16 groups of 8 batches; block (p=bid&7, n=bid>>3) handles groups A=2p
// (batches 16p..+7) and B=2p+1 (batches 16p+8..+15), cols 64n..+63. While A's
// store->flag->poll->volley round trip completes, B computes, and vice versa.
// Volleys stage all 16 batch lanes (fragment order, R12/R14-proven); the 8
// lanes of the other group feed DISCARDED MFMA columns; hm updates gated.
// Waves (ch=w&1, ko=w>>1): W = 16 named VGPR frags via 2-pass fragment-order
// LDS alias. NEW vs R15: xbf has its OWN region (no hbuf alias -- that was
// R15's corruption); redf shrunk 32->16KB via a 2-round K-reduction (waves
// ko>=4 write planes, barrier, waves ko<4 fold in and rewrite, barrier, all
// threads sum 4 planes). All plane accesses lane-stride-4B (conflict-free).
__global__ __launch_bounds__(1024, 1) void rec_persist(
    const bf16_t* __restrict__ h0b, const bf16_t* __restrict__ W,
    bf16_t* __restrict__ EH, float* __restrict__ hfinal,
    const float* __restrict__ rec_b, const float* __restrict__ hi_w, const float* __restrict__ hi_b,
    const float* __restrict__ dtp, const float* __restrict__ ap,
    unsigned* __restrict__ flags)
{
  __shared__ char lds[65536 + 65536 + 16384 + 4352];  // hbufA|hbufB|redf|xbf
  char*  hbufA = lds;
  char*  hbufB = lds + 65536;
  float* redf  = (float*)(lds + 131072);       // 16 KB: 64 planes x 64 lanes
  float* xbf   = (float*)(lds + 147456);       // 16 x 65 f32 (own region)

  const int bid = blockIdx.x;
  const int p   = bid & 7;               // pair index (groups 2p, 2p+1); XCD-local
  const int n   = bid >> 3;              // H tile 0..31
  const int m0  = p * 16;
  const int n0  = n * 64;
  const int tid = threadIdx.x, w = tid >> 6, lane = tid & 63;
  const int l15 = lane & 15, w4 = w*4;
  const int ch = w & 1, ko = w >> 1, ko8 = ko*8;   // compute role

  // ---- one-time: W -> 16 named VGPR frags via 2 fragment-order LDS passes ----
  bf16x8 wE0,wE1,wE2,wE3,wE4,wE5,wE6,wE7;    // cg = ch*2
  bf16x8 wO0,wO1,wO2,wO3,wO4,wO5,wO6,wO7;    // cg = ch*2+1
  #pragma unroll 1
  for (int p2 = 0; p2 < 2; ++p2){
    __syncthreads();
    for (int it = 0; it < 8; ++it){
      int cid = it*1024 + tid;           // 8192 chunks of 16B = 128KB
      int lc  = cid & 63, kk = (cid >> 6) & 63, cgl = cid >> 12;
      uint4 v = *(const uint4*)(W + (size_t)(n0 + p2*32 + cgl*16 + (lc&15))*Hh + kk*32 + ((lc>>4)<<3));
      *(uint4*)(lds + (size_t)cid*16) = v;
    }
    __syncthreads();
    if (p2 == ch){
      #define WRD(i) \
        wE##i = *(const bf16x8*)(lds + (size_t)((     ko8 + (i))*64 + lane)*16); \
        wO##i = *(const bf16x8*)(lds + (size_t)((64 + ko8 + (i))*64 + lane)*16);
      REP8(WRD)
      #undef WRD
    }
  }
  __syncthreads();                       // all W reads done; LDS reusable

  const float s  = 1.f/(1.f + __expf(-dtp[0]));
  const float av = ap[0];
  // output role (R14-proven bijection): 1 element per thread
  const int   cg_o = w & 3, eo = w >> 2;
  const int   batch = m0 + l15;
  const int   col_l = cg_o*16 + ((lane >> 4) << 2) + eo;
  const int   hcol  = n0 + col_l;
  const int   pos   = l15*65 + col_l;
  const float rbv = rec_b[hcol];
  float hm = hi_w[hcol] + hi_b[hcol];
  const bool validA = (l15 < 8), validB = (l15 >= 8);

  // volley source (per-lane scatter, fragment order; R12/R14-proven)
  const size_t vsrc_off = (size_t)(m0 + l15)*Hh + ((lane>>4)<<3);
  // cooperative enc/h slot (R14-proven): tid<512 -> batch tid>>5, col pair tid&31
  const int co_b = m0 + (tid >> 5);
  const int co_c = n0 + (tid & 31)*2;
  // poll pointers: wave (ch,ko) consumes cols [ko*256,+256) -> tiles ko*4..+3
  const unsigned* fpA = flags + (((2*p  )*32) + ko*4 + (lane & 3))*16;
  const unsigned* fpB = flags + (((2*p+1)*32) + ko*4 + (lane & 3))*16;
  unsigned* flA = flags + ((2*p  )*32 + n)*16;
  unsigned* flB = flags + ((2*p+1)*32 + n)*16;

  // volley: wave stages chunks w*4..w*4+3 (full 16 batch lanes)
  auto volley = [&](const bf16_t* Asrc, char* hb){
    const bf16_t* src = Asrc + vsrc_off;
    #pragma unroll
    for (int i = 0; i < 4; ++i)
      gl_lds16(src + (w4 + i)*32, hb + (size_t)(w4 + i)*1024);
  };

  // prologue: stage A(0) from h0; barrier drains it
  volley(h0b, hbufA);
  __syncthreads();

  for (int t = 0; t < Tt; ++t){
    const bf16_t* Aprev = (t==0) ? h0b : (EH + (size_t)(t-1)*(Bb*Hh));
    bf16_t* EHt = EH + (size_t)t*(Bb*Hh);

    // enc for this thread's cooperative slot (both phases; hides under polls)
    u32 ecv = 0;
    if (tid < 512)
      ecv = __hip_atomic_load((const u32*)(EHt + (size_t)co_b*Hh + co_c),
                              __ATOMIC_RELAXED, __HIP_MEMORY_SCOPE_AGENT);

    // poll B producers (step t-1), then issue B volley (drains at R1-A)
    if (t){
      unsigned tt = (unsigned)t;
      for (;;){
        unsigned v = __hip_atomic_load(fpB, __ATOMIC_RELAXED, __HIP_MEMORY_SCOPE_AGENT);
        if (__all((int)(v >= tt))) break;
        __builtin_amdgcn_s_sleep(2);
      }
    }
    volley(Aprev, hbufB);

    // ================= phase A (group 2p, batches l15<8) =================
    {
      f32x4_t aE = {0.f,0.f,0.f,0.f}, aO = aE;
      #define KS(i) { \
        bf16x8 hv = *(const bf16x8*)(hbufA + (size_t)(ko8 + (i))*1024 + (size_t)lane*16); \
        aE = __builtin_amdgcn_mfma_f32_16x16x32_bf16(wE##i, hv, aE, 0,0,0); \
        aO = __builtin_amdgcn_mfma_f32_16x16x32_bf16(wO##i, hv, aO, 0,0,0); }
      REP8(KS)
      #undef KS
      if (ko >= 4){                      // round-1 planes (kp = ko-4)
        #pragma unroll
        for (int e=0;e<4;++e){
          redf[(((ko-4)*4 + ch*2    )*4 + e)*64 + lane] = aE[e];
          redf[(((ko-4)*4 + ch*2 + 1)*4 + e)*64 + lane] = aO[e];
        }
      }
      if (tid < 256){
        xbf[(tid>>5)*65 + (tid&31)*2    ] = b2f((unsigned short)(ecv & 0xffffu));
        xbf[(tid>>5)*65 + (tid&31)*2 + 1] = b2f((unsigned short)(ecv >> 16));
      }
      __syncthreads();                   // R1-A (drains B volley + ecv too)
      if (ko < 4){                       // fold partner, rewrite same slots
        #pragma unroll
        for (int e=0;e<4;++e){
          aE[e] += redf[((ko*4 + ch*2    )*4 + e)*64 + lane];
          aO[e] += redf[((ko*4 + ch*2 + 1)*4 + e)*64 + lane];
        }
        #pragma unroll
        for (int e=0;e<4;++e){
          redf[((ko*4 + ch*2    )*4 + e)*64 + lane] = aE[e];
          redf[((ko*4 + ch*2 + 1)*4 + e)*64 + lane] = aO[e];
        }
      }
      __syncthreads();                   // R2-A
      float fa = 0.f;
      #pragma unroll
      for (int kp=0;kp<4;++kp) fa += redf[((kp*4 + cg_o)*4 + eo)*64 + lane];
      {
        float enc = xbf[pos];
        float pre = enc + av*(fa + rbv);
        float th  = 1.f - 2.f/(__expf(2.f*pre) + 1.f);   // tanh
        if (validA){ hm = (1.f - s)*hm + s*th; xbf[pos] = hm; }
      }
      __syncthreads();                   // C-A: h values in exchange
      if (tid < 256){
        float h0f = xbf[(tid>>5)*65 + (tid&31)*2];
        float h1f = xbf[(tid>>5)*65 + (tid&31)*2 + 1];
        u32 ov = (u32)f2bbits(h0f) | ((u32)f2bbits(h1f) << 16);
        __hip_atomic_store((u32*)(EHt + (size_t)co_b*Hh + co_c), ov,
                           __ATOMIC_RELAXED, __HIP_MEMORY_SCOPE_AGENT);
      }
      __syncthreads();                   // D-A: stores drained
      if (tid == 0)
        __hip_atomic_store(flA, (unsigned)(t+1), __ATOMIC_RELAXED, __HIP_MEMORY_SCOPE_AGENT);
    }

    // ================= phase B (group 2p+1, batches l15>=8) ==============
    {
      f32x4_t aE = {0.f,0.f,0.f,0.f}, aO = aE;
      #define KS(i) { \
        bf16x8 hv = *(const bf16x8*)(hbufB + (size_t)(ko8 + (i))*1024 + (size_t)lane*16); \
        aE = __builtin_amdgcn_mfma_f32_16x16x32_bf16(wE##i, hv, aE, 0,0,0); \
        aO = __builtin_amdgcn_mfma_f32_16x16x32_bf16(wO##i, hv, aO, 0,0,0); }
      REP8(KS)
      #undef KS
      if (ko >= 4){
        #pragma unroll
        for (int e=0;e<4;++e){
          redf[(((ko-4)*4 + ch*2    )*4 + e)*64 + lane] = aE[e];
          redf[(((ko-4)*4 + ch*2 + 1)*4 + e)*64 + lane] = aO[e];
        }
      }
      if (tid >= 256 && tid < 512){
        xbf[(tid>>5)*65 + (tid&31)*2    ] = b2f((unsigned short)(ecv & 0xffffu));
        xbf[(tid>>5)*65 + (tid&31)*2 + 1] = b2f((unsigned short)(ecv >> 16));
      }
      __syncthreads();                   // R1-B
      if (ko < 4){
        #pragma unroll
        for (int e=0;e<4;++e){
          aE[e] += redf[((ko*4 + ch*2    )*4 + e)*64 + lane];
          aO[e] += redf[((ko*4 + ch*2 + 1)*4 + e)*64 + lane];
        }
        #pragma unroll
        for (int e=0;e<4;++e){
          redf[((ko*4 + ch*2    )*4 + e)*64 + lane] = aE[e];
          redf[((ko*4 + ch*2 + 1)*4 + e)*64 + lane] = aO[e];
        }
      }
      __syncthreads();                   // R2-B
      float fa = 0.f;
      #pragma unroll
      for (int kp=0;kp<4;++kp) fa += redf[((kp*4 + cg_o)*4 + eo)*64 + lane];
      {
        float enc = xbf[pos];
        float pre = enc + av*(fa + rbv);
        float th  = 1.f - 2.f/(__expf(2.f*pre) + 1.f);   // tanh
        if (validB){ hm = (1.f - s)*hm + s*th; xbf[pos] = hm; }
      }
      __syncthreads();                   // C-B
      if (tid >= 256 && tid < 512){
        float h0f = xbf[(tid>>5)*65 + (tid&31)*2];
        float h1f = xbf[(tid>>5)*65 + (tid&31)*2 + 1];
        u32 ov = (u32)f2bbits(h0f) | ((u32)f2bbits(h1f) << 16);
        __hip_atomic_store((u32*)(EHt + (size_t)co_b*Hh + co_c), ov,
                           __ATOMIC_RELAXED, __HIP_MEMORY_SCOPE_AGENT);
      }
      // prefetch A(t+1) while B's stores drain: poll A(t+1), issue volley;
      // D-B's implicit vmcnt(0) drains stores AND the volley concurrently.
      if (t+1 < Tt){
        unsigned tt = (unsigned)(t+1);
        for (;;){
          unsigned v = __hip_atomic_load(fpA, __ATOMIC_RELAXED, __HIP_MEMORY_SCOPE_AGENT);
          if (__all((int)(v >= tt))) break;
          __builtin_amdgcn_s_sleep(2);
        }
        volley(EHt, hbufA);
      }
      __syncthreads();                   // D-B: stores + A-volley drained
      if (tid == 0)
        __hip_atomic_store(flB, (unsigned)(t+1), __ATOMIC_RELAXED, __HIP_MEMORY_SCOPE_AGENT);
    }
  }

  // final hidden (f32) -> out tail
  hfinal[(size_t)batch*Hh + hcol] = hm;
}

// ---------- launch ----------
extern "C" void kernel_launch(void* const* d_in, const int* in_sizes, int n_in,
                              void* d_out, int out_size, void* d_ws, size_t ws_size,
                              hipStream_t stream){
  const float* x     = (const float*)d_in[0];
  const float* dt    = (const float*)d_in[1];
  const float* a     = (const float*)d_in[2];
  const float* enc_w = (const float*)d_in[3];
  const float* enc_b = (const float*)d_in[4];
  const float* rec_w = (const float*)d_in[5];
  const float* rec_b = (const float*)d_in[6];
  const float* dec_w = (const float*)d_in[7];
  const float* dec_b = (const float*)d_in[8];
  const float* hi_w  = (const float*)d_in[9];
  const float* hi_b  = (const float*)d_in[10];
  float* out = (float*)d_out;

  // workspace carve-out (~333 MB)
  char* ws = (char*)d_ws;
  size_t off = 0;
  auto carve = [&](size_t bytes)->char*{ char* p = ws + off; off += (bytes + 255) & ~(size_t)255; return p; };
  bf16_t* x_tm   = (bf16_t*)carve((size_t)Tt*Bb*Ii*2);   // 64 MB
  bf16_t* EH     = (bf16_t*)carve((size_t)Tt*Bb*Hh*2);   // 256 MB  enc -> h history
  bf16_t* h0b    = (bf16_t*)carve((size_t)Bb*Hh*2);
  bf16_t* enc_wb = (bf16_t*)carve((size_t)Hh*Ii*2);
  bf16_t* rec_wb = (bf16_t*)carve((size_t)Hh*Hh*2);
  bf16_t* dec_wb = (bf16_t*)carve((size_t)Oo*Hh*2);
  unsigned* flags = (unsigned*)carve(16*32*16*4);         // per-(group,block) flags
  if (off > ws_size) return;  // diagnostic: leaves output zeroed

  // reset flags every call (ws is not re-poisoned between replays)
  hipMemsetAsync(flags, 0, 16*32*16*4, stream);

  // weights -> bf16
  k_f2b<<<(Hh*Ii)/1024, 256, 0, stream>>>(enc_wb, enc_w);
  k_f2b<<<(Hh*Hh)/1024, 256, 0, stream>>>(rec_wb, rec_w);
  k_f2b<<<(Oo*Hh)/1024, 256, 0, stream>>>(dec_wb, dec_w);
  k_init_h0<<<Hh/256, 256, 0, stream>>>(hi_w, hi_b, h0b);
  k_convert_x<<<((size_t)Tt*Bb*Ii/8)/256, 256, 0, stream>>>(x, x_tm);

  // encoder: EH[t*B+b, h] = x_tm @ enc_w^T + enc_b   (M=65536, K=512, N=2048)
  gemm128<0><<<dim3((Tt*Bb)/128, Hh/128), 256, 0, stream>>>(x_tm, Ii, enc_wb, Ii, enc_b, EH, Hh, Ii);

  // recurrence: one persistent cooperative kernel, 512 steps, 1024 threads/block
  {
    float* hfinal = out + (size_t)Tt*Bb*Oo;
    void* args[] = { (void*)&h0b, (void*)&rec_wb, (void*)&EH, (void*)&hfinal,
                     (void*)&rec_b, (void*)&hi_w, (void*)&hi_b, (void*)&dt, (void*)&a,
                     (void*)&flags };
    hipLaunchCooperativeKernel((const void*)rec_persist, dim3(REC_GRID), dim3(1024), args, 0, stream);
  }

  // decoder: out[t*B+b, o] = EH @ dec_w^T + dec_b   (M=65536, K=2048, N=512)
  gemm128<1><<<dim3((Tt*Bb)/128, Oo/128), 256, 0, stream>>>(EH, Hh, dec_wb, Hh, dec_b, out, Oo, Hh);
}

// Round 17
// 3759.170 us; speedup vs baseline: 1.1202x; 1.1202x over previous
//
#include <hip/hip_runtime.h>
#include <hip/hip_bf16.h>
#include <cmath>

// Problem dims
#define Bb 128
#define Tt 512
#define Ii 512
#define Hh 2048
#define Oo 512
#define REC_GRID 256

typedef __bf16 bf16_t;
typedef __bf16 bf16x8 __attribute__((ext_vector_type(8)));
typedef __bf16 bf16x4 __attribute__((ext_vector_type(4)));
typedef float  f32x4_t __attribute__((ext_vector_type(4)));
typedef unsigned u32;

static __device__ __forceinline__ bf16_t to_b(float v){ return (bf16_t)v; }
static __device__ __forceinline__ float  b2f(unsigned short u){ unsigned x = ((unsigned)u)<<16; return __builtin_bit_cast(float, x); }
static __device__ __forceinline__ unsigned short f2bbits(float v){ return __builtin_bit_cast(unsigned short, to_b(v)); }

// async global->LDS, 16B per lane: LDS dest = uniform base + lane*16, global
// source is PER-LANE (T21/m173) -- fragment-order landing via source scatter.
static __device__ __forceinline__ void gl_lds16(const void* g, void* l){
  __builtin_amdgcn_global_load_lds((const __attribute__((address_space(1))) void*)g,
                                   (__attribute__((address_space(3))) void*)l, 16, 0, 0);
}

#define REP4(M) M(0)M(1)M(2)M(3)

// ---------- small prep kernels ----------
__global__ __launch_bounds__(256) void k_f2b(bf16_t* __restrict__ dst, const float* __restrict__ src){
  size_t i = ((size_t)blockIdx.x*256 + threadIdx.x)*4;
  float4 v = *(const float4*)(src + i);
  bf16x4 o; o[0]=to_b(v.x); o[1]=to_b(v.y); o[2]=to_b(v.z); o[3]=to_b(v.w);
  *(bf16x4*)(dst + i) = o;
}

__global__ __launch_bounds__(256) void k_init_h0(const float* __restrict__ hi_w, const float* __restrict__ hi_b,
                                                 bf16_t* __restrict__ h0b){
  int i = blockIdx.x*256 + threadIdx.x;           // [0, H)
  bf16_t vb = to_b(hi_w[i] + hi_b[i]);
  for (int b=0;b<Bb;++b) h0b[(size_t)b*Hh + i] = vb;
}

__global__ __launch_bounds__(256) void k_convert_x(const float* __restrict__ x, bf16_t* __restrict__ x_tm){
  size_t idx = ((size_t)blockIdx.x*256 + threadIdx.x)*8;
  int    i0  = (int)(idx % Ii);
  size_t m   = idx / Ii;                          // m = t*B + b
  int    t   = (int)(m / Bb), b = (int)(m % Bb);
  const float* s = x + ((size_t)b*Tt + t)*Ii + i0;
  float4 v0 = *(const float4*)s, v1 = *(const float4*)(s+4);
  bf16x8 o;
  o[0]=to_b(v0.x); o[1]=to_b(v0.y); o[2]=to_b(v0.z); o[3]=to_b(v0.w);
  o[4]=to_b(v1.x); o[5]=to_b(v1.y); o[6]=to_b(v1.z); o[7]=to_b(v1.w);
  *(bf16x8*)(x_tm + idx) = o;
}

// ---------- GEMM building blocks (encoder / decoder) ----------
template<int ROWS, int KB>
static __device__ __forceinline__ void stage(const bf16_t* __restrict__ g, long ld, long row0, int k0,
                                             char* __restrict__ ldsT){
  constexpr int SLOTS = KB/8;
  constexpr int PT    = ROWS*SLOTS/256;
  #pragma unroll
  for (int j=0;j<PT;++j){
    int c    = threadIdx.x + 256*j;
    int row  = c / SLOTS, slot = c % SLOTS;
    uint4 v  = *(const uint4*)(g + (row0+row)*ld + k0 + slot*8);
    *(uint4*)(ldsT + row*(KB*2) + ((slot*16) ^ ((row&7)<<4))) = v;
  }
}

template<int KB>
static __device__ __forceinline__ bf16x8 frag(const char* __restrict__ ldsT, int row, int kk, int lane){
  int kbyte = kk*64 + ((lane>>4)<<4);
  return *(const bf16x8*)(ldsT + row*(KB*2) + (kbyte ^ ((row&7)<<4)));
}

template<int EPI>
__global__ __launch_bounds__(256) void gemm128(const bf16_t* __restrict__ A, long lda,
                                               const bf16_t* __restrict__ Bw, long ldb,
                                               const float* __restrict__ bias,
                                               void* __restrict__ Cout, long ldc, int K){
  constexpr int TM=128, TN=128, KB=64;
  __shared__ char lds[(TM+TN)*KB*2];
  char* ldsA = lds;
  char* ldsB = lds + TM*KB*2;
  long m0 = (long)blockIdx.x * TM;
  long n0 = (long)blockIdx.y * TN;
  int w = threadIdx.x >> 6, lane = threadIdx.x & 63;
  int wm = w >> 1, wn = w & 1;
  f32x4_t acc[4][4] = {};
  for (int k0=0;k0<K;k0+=KB){
    __syncthreads();
    stage<TM,KB>(A,  lda, m0, k0, ldsA);
    stage<TN,KB>(Bw, ldb, n0, k0, ldsB);
    __syncthreads();
    #pragma unroll
    for (int kk=0;kk<KB/32;++kk){
      bf16x8 af[4], bfv[4];
      #pragma unroll
      for (int f=0;f<4;++f){ int r = wm*64 + f*16 + (lane&15); af[f]  = frag<KB>(ldsA, r, kk, lane); }
      #pragma unroll
      for (int f=0;f<4;++f){ int r = wn*64 + f*16 + (lane&15); bfv[f] = frag<KB>(ldsB, r, kk, lane); }
      #pragma unroll
      for (int i=0;i<4;++i)
        #pragma unroll
        for (int j=0;j<4;++j)
          acc[i][j] = __builtin_amdgcn_mfma_f32_16x16x32_bf16(af[i], bfv[j], acc[i][j], 0,0,0);
    }
  }
  #pragma unroll
  for (int i=0;i<4;++i)
    #pragma unroll
    for (int j=0;j<4;++j)
      #pragma unroll
      for (int e=0;e<4;++e){
        long row = m0 + wm*64 + i*16 + ((lane>>4)<<2) + e;
        long col = n0 + wn*64 + j*16 + (lane&15);
        float v = acc[i][j][e] + bias[col];
        if (EPI==0) ((bf16_t*)Cout)[row*ldc + col] = to_b(v);
        else        ((float*) Cout)[row*ldc + col] = v;
      }
}

// ---------- persistent recurrence kernel (1024 threads / 16 waves) ----------
// R14 structure (proven: 8 groups x 32 blocks, g=bid&7; group g owns batches
// 16g..+15; block (g,n) owns H-cols 64n..+63; wave w = K-sixteenth with W =
// 16 named VGPR frags via 2-pass fragment-order LDS alias; wave-private
// fragment-order volley; 64KB scalar-plane reduction) with a collapsed sync
// tail:
//  * epilogue re-mapped so 8 waves own 2 ADJACENT cols/thread -> the u32
//    enc-load/h-store belongs to the computing thread: no xbf exchange, no
//    barriers C/D. Epilogue = 32 plane reads -> tanh -> u32 agent store ->
//    wave vmcnt(0) -> per-epilogue-wave flag (8/block; consumers poll 16).
//  * poll+volley for t+1 sits between B1 and B2: non-epilogue waves prefetch
//    while epilogue finishes; B2's implicit per-wave vmcnt drains the volley
//    and separates plane-read(t) from plane-write(t+1). 2 barriers/step.
__global__ __launch_bounds__(1024, 1) void rec_persist(
    const bf16_t* __restrict__ h0b, const bf16_t* __restrict__ W,
    bf16_t* __restrict__ EH, float* __restrict__ hfinal,
    const float* __restrict__ rec_b, const float* __restrict__ hi_w, const float* __restrict__ hi_b,
    const float* __restrict__ dtp, const float* __restrict__ ap,
    unsigned* __restrict__ flags)
{
  __shared__ char lds[131072];           // init: W pass buffer; steady: hbuf|redf
  char*  hbuf = lds;                     // 64 KB volley (64 chunks x 1KB)
  float* redf = (float*)(lds + 65536);   // 64 KB: 256 planes x 64 lanes

  const int bid = blockIdx.x;
  const int g   = bid & 7;               // batch group (XCD-local heuristic)
  const int n   = bid >> 3;              // H tile 0..31
  const int m0  = g * 16;
  const int n0  = n * 64;
  unsigned* gflags = flags + g*256*16;   // 32 blocks x 8 epi-waves, 64B stride
  const int tid = threadIdx.x, w = tid >> 6, lane = tid & 63;
  const int l15 = lane & 15, w4 = w*4;

  // ---- one-time: W -> 16 named VGPR frags via 2 fragment-order LDS passes ----
  #define WDCL(i) bf16x8 wa##i, wb##i, wc##i, wd##i;
  REP4(WDCL)
  #undef WDCL
  #pragma unroll 1
  for (int p = 0; p < 2; ++p){
    __syncthreads();
    for (int it = 0; it < 8; ++it){
      int cid = it*1024 + tid;           // 8192 chunks of 16B = 128KB
      int lc  = cid & 63, kk = (cid >> 6) & 63, cgl = cid >> 12;
      uint4 v = *(const uint4*)(W + (size_t)(n0 + p*32 + cgl*16 + (lc&15))*Hh + kk*32 + ((lc>>4)<<3));
      *(uint4*)(lds + (size_t)cid*16) = v;
    }
    __syncthreads();
    if (p == 0){
      #define WRD(i) \
        wa##i = *(const bf16x8*)(lds + (size_t)((     w4 + (i))*64 + lane)*16); \
        wb##i = *(const bf16x8*)(lds + (size_t)((64 + w4 + (i))*64 + lane)*16);
      REP4(WRD)
      #undef WRD
    } else {
      #define WRD(i) \
        wc##i = *(const bf16x8*)(lds + (size_t)((     w4 + (i))*64 + lane)*16); \
        wd##i = *(const bf16x8*)(lds + (size_t)((64 + w4 + (i))*64 + lane)*16);
      REP4(WRD)
      #undef WRD
    }
  }
  __syncthreads();                       // all W reads done; LDS reusable

  const float s  = 1.f/(1.f + __expf(-dtp[0]));
  const float av = ap[0];
  // epilogue role (w < 8 only): 2 adjacent cols per thread
  const int   cg_o = w & 3, ep = (w >> 2) & 1;
  const int   batch = m0 + l15;
  const int   c0    = cg_o*16 + ((lane >> 4) << 2) + ep*2;   // local col (even)
  const size_t eoff = (size_t)batch*Hh + n0 + c0;            // enc/h u32 address
  float rb0 = 0.f, rb1 = 0.f, hm0 = 0.f, hm1 = 0.f;
  if (w < 8){
    rb0 = rec_b[n0 + c0];     rb1 = rec_b[n0 + c0 + 1];
    hm0 = hi_w[n0 + c0] + hi_b[n0 + c0];
    hm1 = hi_w[n0 + c0 + 1] + hi_b[n0 + c0 + 1];
  }

  // volley source (per-lane scatter, fragment order; R12/R14-proven)
  const size_t vsrc_off = (size_t)(m0 + l15)*Hh + ((lane>>4)<<3);
  // poll: wave w consumes cols [w*128,+128) = blocks 2w,2w+1; 8 epi-flags each
  const unsigned* fp = gflags + ((w*2 + ((lane>>3)&1))*8 + (lane&7))*16;
  unsigned* myflag = gflags + (n*8 + w)*16;                  // valid for w<8

  // prologue: stage h0 into wave-private chunks, drain
  {
    const bf16_t* src = h0b + vsrc_off;
    #pragma unroll
    for (int i = 0; i < 4; ++i)
      gl_lds16(src + (w4 + i)*32, hbuf + (size_t)(w4 + i)*1024);
  }
  asm volatile("s_waitcnt vmcnt(0)" ::: "memory");

  for (int t = 0; t < Tt; ++t){
    bf16_t* EHt = EH + (size_t)t*(Bb*Hh);

    // enc prefetch (own slot; no producer hazard; hides under KS)
    u32 ecv = 0;
    if (w < 8)
      ecv = __hip_atomic_load((const u32*)(EHt + eoff),
                              __ATOMIC_RELAXED, __HIP_MEMORY_SCOPE_AGENT);

    // K-loop: 4 conflict-free h ds_reads, 16 MFMAs (4 col-groups x 4 kk)
    f32x4_t acc0 = {0.f,0.f,0.f,0.f}, acc1 = acc0, acc2 = acc0, acc3 = acc0;
    #define KS(i) { \
      bf16x8 hv = *(const bf16x8*)(hbuf + (size_t)(w4 + (i))*1024 + (size_t)lane*16); \
      acc0 = __builtin_amdgcn_mfma_f32_16x16x32_bf16(wa##i, hv, acc0, 0,0,0); \
      acc1 = __builtin_amdgcn_mfma_f32_16x16x32_bf16(wb##i, hv, acc1, 0,0,0); \
      acc2 = __builtin_amdgcn_mfma_f32_16x16x32_bf16(wc##i, hv, acc2, 0,0,0); \
      acc3 = __builtin_amdgcn_mfma_f32_16x16x32_bf16(wd##i, hv, acc3, 0,0,0); }
    REP4(KS)
    #undef KS

    // K-reduction planes (R14 exact layout; lane-stride-4B, conflict-free)
    #pragma unroll
    for (int e=0;e<4;++e){
      redf[(w*16 +  0 + e)*64 + lane] = acc0[e];
      redf[(w*16 +  4 + e)*64 + lane] = acc1[e];
      redf[(w*16 +  8 + e)*64 + lane] = acc2[e];
      redf[(w*16 + 12 + e)*64 + lane] = acc3[e];
    }
    __syncthreads();                     // B1: planes visible

    if (w < 8){
      // sum 16 K-partials for each of this thread's 2 cols
      float fa0 = 0.f, fa1 = 0.f;
      #pragma unroll
      for (int q=0;q<16;++q){
        fa0 += redf[(q*16 + cg_o*4 + ep*2    )*64 + lane];
        fa1 += redf[(q*16 + cg_o*4 + ep*2 + 1)*64 + lane];
      }
      // gated tanh update; direct u32 agent store (own slot)
      float enc0 = b2f((unsigned short)(ecv & 0xffffu));
      float enc1 = b2f((unsigned short)(ecv >> 16));
      float pre0 = enc0 + av*(fa0 + rb0);
      float pre1 = enc1 + av*(fa1 + rb1);
      float th0  = 1.f - 2.f/(__expf(2.f*pre0) + 1.f);
      float th1  = 1.f - 2.f/(__expf(2.f*pre1) + 1.f);
      hm0 = (1.f - s)*hm0 + s*th0;
      hm1 = (1.f - s)*hm1 + s*th1;
      u32 ov = (u32)f2bbits(hm0) | ((u32)f2bbits(hm1) << 16);
      __hip_atomic_store((u32*)(EHt + eoff), ov,
                         __ATOMIC_RELAXED, __HIP_MEMORY_SCOPE_AGENT);
      asm volatile("s_waitcnt vmcnt(0)" ::: "memory");   // own stores acked
      if (lane == 0)
        __hip_atomic_store(myflag, (unsigned)(t+1),
                           __ATOMIC_RELAXED, __HIP_MEMORY_SCOPE_AGENT);
    }

    // prefetch next step (overlaps epilogue for non-epilogue waves)
    if (t+1 < Tt){
      unsigned tt = (unsigned)(t+1);
      for (;;){
        unsigned v = __hip_atomic_load(fp, __ATOMIC_RELAXED, __HIP_MEMORY_SCOPE_AGENT);
        if (__all((int)(v >= tt))) break;
        __builtin_amdgcn_s_sleep(2);
      }
      const bf16_t* src = EHt + vsrc_off;     // h(t) just produced
      #pragma unroll
      for (int i = 0; i < 4; ++i)
        gl_lds16(src + (w4 + i)*32, hbuf + (size_t)(w4 + i)*1024);
    }
    __syncthreads();                     // B2: per-wave vmcnt drains volley;
                                         // separates plane-read(t) / write(t+1)
  }

  // final hidden (f32) -> out tail (epilogue threads own 2 cols each)
  if (w < 8){
    float2 hv; hv.x = hm0; hv.y = hm1;
    *(float2*)(hfinal + eoff) = hv;
  }
}

// ---------- launch ----------
extern "C" void kernel_launch(void* const* d_in, const int* in_sizes, int n_in,
                              void* d_out, int out_size, void* d_ws, size_t ws_size,
                              hipStream_t stream){
  const float* x     = (const float*)d_in[0];
  const float* dt    = (const float*)d_in[1];
  const float* a     = (const float*)d_in[2];
  const float* enc_w = (const float*)d_in[3];
  const float* enc_b = (const float*)d_in[4];
  const float* rec_w = (const float*)d_in[5];
  const float* rec_b = (const float*)d_in[6];
  const float* dec_w = (const float*)d_in[7];
  const float* dec_b = (const float*)d_in[8];
  const float* hi_w  = (const float*)d_in[9];
  const float* hi_b  = (const float*)d_in[10];
  float* out = (float*)d_out;

  // workspace carve-out (~333 MB)
  char* ws = (char*)d_ws;
  size_t off = 0;
  auto carve = [&](size_t bytes)->char*{ char* p = ws + off; off += (bytes + 255) & ~(size_t)255; return p; };
  bf16_t* x_tm   = (bf16_t*)carve((size_t)Tt*Bb*Ii*2);   // 64 MB
  bf16_t* EH     = (bf16_t*)carve((size_t)Tt*Bb*Hh*2);   // 256 MB  enc -> h history
  bf16_t* h0b    = (bf16_t*)carve((size_t)Bb*Hh*2);
  bf16_t* enc_wb = (bf16_t*)carve((size_t)Hh*Ii*2);
  bf16_t* rec_wb = (bf16_t*)carve((size_t)Hh*Hh*2);
  bf16_t* dec_wb = (bf16_t*)carve((size_t)Oo*Hh*2);
  unsigned* flags = (unsigned*)carve(8*256*16*4);         // per-(blk,epi-wave) flags
  if (off > ws_size) return;  // diagnostic: leaves output zeroed

  // reset flags every call (ws is not re-poisoned between replays)
  hipMemsetAsync(flags, 0, 8*256*16*4, stream);

  // weights -> bf16
  k_f2b<<<(Hh*Ii)/1024, 256, 0, stream>>>(enc_wb, enc_w);
  k_f2b<<<(Hh*Hh)/1024, 256, 0, stream>>>(rec_wb, rec_w);
  k_f2b<<<(Oo*Hh)/1024, 256, 0, stream>>>(dec_wb, dec_w);
  k_init_h0<<<Hh/256, 256, 0, stream>>>(hi_w, hi_b, h0b);
  k_convert_x<<<((size_t)Tt*Bb*Ii/8)/256, 256, 0, stream>>>(x, x_tm);

  // encoder: EH[t*B+b, h] = x_tm @ enc_w^T + enc_b   (M=65536, K=512, N=2048)
  gemm128<0><<<dim3((Tt*Bb)/128, Hh/128), 256, 0, stream>>>(x_tm, Ii, enc_wb, Ii, enc_b, EH, Hh, Ii);

  // recurrence: one persistent cooperative kernel, 512 steps, 1024 threads/block
  {
    float* hfinal = out + (size_t)Tt*Bb*Oo;
    void* args[] = { (void*)&h0b, (void*)&rec_wb, (void*)&EH, (void*)&hfinal,
                     (void*)&rec_b, (void*)&hi_w, (void*)&hi_b, (void*)&dt, (void*)&a,
                     (void*)&flags };
    hipLaunchCooperativeKernel((const void*)rec_persist, dim3(REC_GRID), dim3(1024), args, 0, stream);
  }

  // decoder: out[t*B+b, o] = EH @ dec_w^T + dec_b   (M=65536, K=2048, N=512)
  gemm128<1><<<dim3((Tt*Bb)/128, Oo/128), 256, 0, stream>>>(EH, Hh, dec_wb, Hh, dec_b, out, Oo, Hh);
}

// Round 18
// 3294.355 us; speedup vs baseline: 1.2782x; 1.1411x over previous
//
#include <hip/hip_runtime.h>
#include <hip/hip_bf16.h>
#include <cmath>

// Problem dims
#define Bb 128
#define Tt 512
#define Ii 512
#define Hh 2048
#define Oo 512
#define REC_GRID 256

typedef __bf16 bf16_t;
typedef __bf16 bf16x8 __attribute__((ext_vector_type(8)));
typedef __bf16 bf16x4 __attribute__((ext_vector_type(4)));
typedef float  f32x4_t __attribute__((ext_vector_type(4)));
typedef unsigned u32;

static __device__ __forceinline__ bf16_t to_b(float v){ return (bf16_t)v; }
static __device__ __forceinline__ float  b2f(unsigned short u){ unsigned x = ((unsigned)u)<<16; return __builtin_bit_cast(float, x); }
static __device__ __forceinline__ unsigned short f2bbits(float v){ return __builtin_bit_cast(unsigned short, to_b(v)); }

// async global->LDS, 16B per lane: LDS dest = uniform base + lane*16, global
// source is PER-LANE (T21/m173) -- fragment-order landing via source scatter.
static __device__ __forceinline__ void gl_lds16(const void* g, void* l){
  __builtin_amdgcn_global_load_lds((const __attribute__((address_space(1))) void*)g,
                                   (__attribute__((address_space(3))) void*)l, 16, 0, 0);
}

#define REP4(M) M(0)M(1)M(2)M(3)

// ---------- small prep kernels ----------
__global__ __launch_bounds__(256) void k_f2b(bf16_t* __restrict__ dst, const float* __restrict__ src){
  size_t i = ((size_t)blockIdx.x*256 + threadIdx.x)*4;
  float4 v = *(const float4*)(src + i);
  bf16x4 o; o[0]=to_b(v.x); o[1]=to_b(v.y); o[2]=to_b(v.z); o[3]=to_b(v.w);
  *(bf16x4*)(dst + i) = o;
}

__global__ __launch_bounds__(256) void k_init_h0(const float* __restrict__ hi_w, const float* __restrict__ hi_b,
                                                 bf16_t* __restrict__ h0b){
  int i = blockIdx.x*256 + threadIdx.x;           // [0, H)
  bf16_t vb = to_b(hi_w[i] + hi_b[i]);
  for (int b=0;b<Bb;++b) h0b[(size_t)b*Hh + i] = vb;
}

__global__ __launch_bounds__(256) void k_convert_x(const float* __restrict__ x, bf16_t* __restrict__ x_tm){
  size_t idx = ((size_t)blockIdx.x*256 + threadIdx.x)*8;
  int    i0  = (int)(idx % Ii);
  size_t m   = idx / Ii;                          // m = t*B + b
  int    t   = (int)(m / Bb), b = (int)(m % Bb);
  const float* s = x + ((size_t)b*Tt + t)*Ii + i0;
  float4 v0 = *(const float4*)s, v1 = *(const float4*)(s+4);
  bf16x8 o;
  o[0]=to_b(v0.x); o[1]=to_b(v0.y); o[2]=to_b(v0.z); o[3]=to_b(v0.w);
  o[4]=to_b(v1.x); o[5]=to_b(v1.y); o[6]=to_b(v1.z); o[7]=to_b(v1.w);
  *(bf16x8*)(x_tm + idx) = o;
}

// ---------- GEMM building blocks (encoder / decoder) ----------
template<int ROWS, int KB>
static __device__ __forceinline__ void stage(const bf16_t* __restrict__ g, long ld, long row0, int k0,
                                             char* __restrict__ ldsT){
  constexpr int SLOTS = KB/8;
  constexpr int PT    = ROWS*SLOTS/256;
  #pragma unroll
  for (int j=0;j<PT;++j){
    int c    = threadIdx.x + 256*j;
    int row  = c / SLOTS, slot = c % SLOTS;
    uint4 v  = *(const uint4*)(g + (row0+row)*ld + k0 + slot*8);
    *(uint4*)(ldsT + row*(KB*2) + ((slot*16) ^ ((row&7)<<4))) = v;
  }
}

template<int KB>
static __device__ __forceinline__ bf16x8 frag(const char* __restrict__ ldsT, int row, int kk, int lane){
  int kbyte = kk*64 + ((lane>>4)<<4);
  return *(const bf16x8*)(ldsT + row*(KB*2) + (kbyte ^ ((row&7)<<4)));
}

template<int EPI>
__global__ __launch_bounds__(256) void gemm128(const bf16_t* __restrict__ A, long lda,
                                               const bf16_t* __restrict__ Bw, long ldb,
                                               const float* __restrict__ bias,
                                               void* __restrict__ Cout, long ldc, int K){
  constexpr int TM=128, TN=128, KB=64;
  __shared__ char lds[(TM+TN)*KB*2];
  char* ldsA = lds;
  char* ldsB = lds + TM*KB*2;
  long m0 = (long)blockIdx.x * TM;
  long n0 = (long)blockIdx.y * TN;
  int w = threadIdx.x >> 6, lane = threadIdx.x & 63;
  int wm = w >> 1, wn = w & 1;
  f32x4_t acc[4][4] = {};
  for (int k0=0;k0<K;k0+=KB){
    __syncthreads();
    stage<TM,KB>(A,  lda, m0, k0, ldsA);
    stage<TN,KB>(Bw, ldb, n0, k0, ldsB);
    __syncthreads();
    #pragma unroll
    for (int kk=0;kk<KB/32;++kk){
      bf16x8 af[4], bfv[4];
      #pragma unroll
      for (int f=0;f<4;++f){ int r = wm*64 + f*16 + (lane&15); af[f]  = frag<KB>(ldsA, r, kk, lane); }
      #pragma unroll
      for (int f=0;f<4;++f){ int r = wn*64 + f*16 + (lane&15); bfv[f] = frag<KB>(ldsB, r, kk, lane); }
      #pragma unroll
      for (int i=0;i<4;++i)
        #pragma unroll
        for (int j=0;j<4;++j)
          acc[i][j] = __builtin_amdgcn_mfma_f32_16x16x32_bf16(af[i], bfv[j], acc[i][j], 0,0,0);
    }
  }
  #pragma unroll
  for (int i=0;i<4;++i)
    #pragma unroll
    for (int j=0;j<4;++j)
      #pragma unroll
      for (int e=0;e<4;++e){
        long row = m0 + wm*64 + i*16 + ((lane>>4)<<2) + e;
        long col = n0 + wn*64 + j*16 + (lane&15);
        float v = acc[i][j][e] + bias[col];
        if (EPI==0) ((bf16_t*)Cout)[row*ldc + col] = to_b(v);
        else        ((float*) Cout)[row*ldc + col] = v;
      }
}

// ---------- persistent recurrence kernel (1024 threads / 16 waves) ----------
// R14 structure (best measured: 8 groups x 32 blocks, g=bid&7; group g owns
// batches 16g..+15; block (g,n) owns H-cols 64n..+63; wave w = K-sixteenth,
// W = 16 named VGPR frags via 2-pass fragment-order LDS alias; wave-private
// fragment-order volley; 64KB scalar-plane reduction; COALESCED u32 exchange
// epilogue) with two R17-proven sync grafts:
//  * per-epilogue-wave flags: the 8 storing waves drain own stores and raise
//    own flags right after barrier C (no barrier D, no block-wide drain on
//    the producer->flag path). Consumers poll 2 blocks x 8 wave-flags.
//  * poll+volley for t+1 moved after barrier C: non-storing waves prefetch
//    while storing waves finish; loop-end barrier drains the volley.
__global__ __launch_bounds__(1024, 1) void rec_persist(
    const bf16_t* __restrict__ h0b, const bf16_t* __restrict__ W,
    bf16_t* __restrict__ EH, float* __restrict__ hfinal,
    const float* __restrict__ rec_b, const float* __restrict__ hi_w, const float* __restrict__ hi_b,
    const float* __restrict__ dtp, const float* __restrict__ ap,
    unsigned* __restrict__ flags)
{
  __shared__ char lds[65536 + 65536 + 4352];   // hbuf | redf | xbf
  char*  hbuf = lds;                           // 64 KB volley (64 chunks x 1KB)
  float* redf = (float*)(lds + 65536);         // 64 KB: 256 planes x 64 lanes
  float* xbf  = (float*)(lds + 131072);        // 16 x 65 padded exchange

  const int bid = blockIdx.x;
  const int g   = bid & 7;               // batch group (XCD-local heuristic)
  const int n   = bid >> 3;              // H tile 0..31
  const int m0  = g * 16;
  const int n0  = n * 64;
  unsigned* gflags = flags + g*256*16;   // 32 blocks x 8 epi-waves, 64B stride
  const int tid = threadIdx.x, w = tid >> 6, lane = tid & 63;
  const int l15 = lane & 15, w4 = w*4;

  // ---- one-time: W -> 16 named VGPR frags via 2 fragment-order LDS passes ----
  #define WDCL(i) bf16x8 wa##i, wb##i, wc##i, wd##i;
  REP4(WDCL)
  #undef WDCL
  #pragma unroll 1
  for (int p = 0; p < 2; ++p){
    __syncthreads();
    for (int it = 0; it < 8; ++it){
      int cid = it*1024 + tid;           // 8192 chunks of 16B = 128KB
      int lc  = cid & 63, kk = (cid >> 6) & 63, cgl = cid >> 12;
      uint4 v = *(const uint4*)(W + (size_t)(n0 + p*32 + cgl*16 + (lc&15))*Hh + kk*32 + ((lc>>4)<<3));
      *(uint4*)(lds + (size_t)cid*16) = v;
    }
    __syncthreads();
    if (p == 0){
      #define WRD(i) \
        wa##i = *(const bf16x8*)(lds + (size_t)((     w4 + (i))*64 + lane)*16); \
        wb##i = *(const bf16x8*)(lds + (size_t)((64 + w4 + (i))*64 + lane)*16);
      REP4(WRD)
      #undef WRD
    } else {
      #define WRD(i) \
        wc##i = *(const bf16x8*)(lds + (size_t)((     w4 + (i))*64 + lane)*16); \
        wd##i = *(const bf16x8*)(lds + (size_t)((64 + w4 + (i))*64 + lane)*16);
      REP4(WRD)
      #undef WRD
    }
  }
  __syncthreads();                       // all W reads done; LDS reusable

  const float s  = 1.f/(1.f + __expf(-dtp[0]));
  const float av = ap[0];
  // output role (R14-proven bijection): 1 element per thread
  const int   cg_o = w & 3, eo = w >> 2;
  const int   batch = m0 + l15;
  const int   col_l = cg_o*16 + ((lane >> 4) << 2) + eo;
  const int   hcol  = n0 + col_l;
  const int   pos   = l15*65 + col_l;
  const float rbv = rec_b[hcol];
  float hm = hi_w[hcol] + hi_b[hcol];

  // volley source (per-lane scatter, fragment order; R12/R14-proven)
  const size_t vsrc_off = (size_t)(m0 + l15)*Hh + ((lane>>4)<<3);
  // cooperative enc/h slot (R14-proven): tid<512 -> batch tid>>5, col pair tid&31
  const int co_b = m0 + (tid >> 5);
  const int co_c = n0 + (tid & 31)*2;
  // poll: wave w consumes cols [w*128,+128) = blocks 2w,2w+1; 8 epi-flags each
  const unsigned* fp = gflags + ((w*2 + ((lane>>3)&1))*8 + (lane&7))*16;
  unsigned* myflag = gflags + (n*8 + w)*16;                  // valid for w<8

  // prologue: stage h0 into wave-private chunks, drain
  {
    const bf16_t* src = h0b + vsrc_off;
    #pragma unroll
    for (int i = 0; i < 4; ++i)
      gl_lds16(src + (w4 + i)*32, hbuf + (size_t)(w4 + i)*1024);
  }
  asm volatile("s_waitcnt vmcnt(0)" ::: "memory");

  for (int t = 0; t < Tt; ++t){
    bf16_t* EHt = EH + (size_t)t*(Bb*Hh);

    // enc for this thread's cooperative slot (uncached agent load; hides under KS)
    u32 ecv = 0;
    if (tid < 512)
      ecv = __hip_atomic_load((const u32*)(EHt + (size_t)co_b*Hh + co_c),
                              __ATOMIC_RELAXED, __HIP_MEMORY_SCOPE_AGENT);

    // K-loop: 4 conflict-free h ds_reads, 16 MFMAs (4 col-groups x 4 kk)
    f32x4_t acc0 = {0.f,0.f,0.f,0.f}, acc1 = acc0, acc2 = acc0, acc3 = acc0;
    #define KS(i) { \
      bf16x8 hv = *(const bf16x8*)(hbuf + (size_t)(w4 + (i))*1024 + (size_t)lane*16); \
      acc0 = __builtin_amdgcn_mfma_f32_16x16x32_bf16(wa##i, hv, acc0, 0,0,0); \
      acc1 = __builtin_amdgcn_mfma_f32_16x16x32_bf16(wb##i, hv, acc1, 0,0,0); \
      acc2 = __builtin_amdgcn_mfma_f32_16x16x32_bf16(wc##i, hv, acc2, 0,0,0); \
      acc3 = __builtin_amdgcn_mfma_f32_16x16x32_bf16(wd##i, hv, acc3, 0,0,0); }
    REP4(KS)
    #undef KS

    // K-reduction planes (R14 exact layout; lane-stride-4B, conflict-free)
    #pragma unroll
    for (int e=0;e<4;++e){
      redf[(w*16 +  0 + e)*64 + lane] = acc0[e];
      redf[(w*16 +  4 + e)*64 + lane] = acc1[e];
      redf[(w*16 +  8 + e)*64 + lane] = acc2[e];
      redf[(w*16 + 12 + e)*64 + lane] = acc3[e];
    }
    if (tid < 512){
      xbf[(tid>>5)*65 + (tid&31)*2    ] = b2f((unsigned short)(ecv & 0xffffu));
      xbf[(tid>>5)*65 + (tid&31)*2 + 1] = b2f((unsigned short)(ecv >> 16));
    }
    __syncthreads();                     // B1: planes + enc exchange visible

    float fa = 0.f;
    #pragma unroll
    for (int q=0;q<16;++q) fa += redf[(q*16 + cg_o*4 + eo)*64 + lane];

    // gated tanh update (1 element/thread); same-thread read-then-write xbf[pos]
    {
      float enc = xbf[pos];
      float pre = enc + av*(fa + rbv);
      float th  = 1.f - 2.f/(__expf(2.f*pre) + 1.f);   // tanh
      hm = (1.f - s)*hm + s*th;
      xbf[pos] = hm;
    }
    __syncthreads();                     // C: h values in exchange

    // storing waves: coalesced u32 store, own drain, own flag (no barrier D)
    if (tid < 512){
      float h0f = xbf[(tid>>5)*65 + (tid&31)*2];
      float h1f = xbf[(tid>>5)*65 + (tid&31)*2 + 1];
      u32 ov = (u32)f2bbits(h0f) | ((u32)f2bbits(h1f) << 16);
      __hip_atomic_store((u32*)(EHt + (size_t)co_b*Hh + co_c), ov,
                         __ATOMIC_RELAXED, __HIP_MEMORY_SCOPE_AGENT);
      asm volatile("s_waitcnt vmcnt(0)" ::: "memory");   // own stores acked
      if (lane == 0)
        __hip_atomic_store(myflag, (unsigned)(t+1),
                           __ATOMIC_RELAXED, __HIP_MEMORY_SCOPE_AGENT);
    }

    // prefetch next step (non-storing waves start immediately after C)
    if (t+1 < Tt){
      unsigned tt = (unsigned)(t+1);
      for (;;){
        unsigned v = __hip_atomic_load(fp, __ATOMIC_RELAXED, __HIP_MEMORY_SCOPE_AGENT);
        if (__all((int)(v >= tt))) break;
        __builtin_amdgcn_s_sleep(2);
      }
      const bf16_t* src = EHt + vsrc_off;     // h(t) just produced
      #pragma unroll
      for (int i = 0; i < 4; ++i)
        gl_lds16(src + (w4 + i)*32, hbuf + (size_t)(w4 + i)*1024);
    }
    __syncthreads();                     // B2: per-wave vmcnt drains volley;
                                         // separates plane/xbf (t) vs (t+1)
  }

  // final hidden (f32) -> out tail (1 element/thread)
  hfinal[(size_t)batch*Hh + hcol] = hm;
}

// ---------- launch ----------
extern "C" void kernel_launch(void* const* d_in, const int* in_sizes, int n_in,
                              void* d_out, int out_size, void* d_ws, size_t ws_size,
                              hipStream_t stream){
  const float* x     = (const float*)d_in[0];
  const float* dt    = (const float*)d_in[1];
  const float* a     = (const float*)d_in[2];
  const float* enc_w = (const float*)d_in[3];
  const float* enc_b = (const float*)d_in[4];
  const float* rec_w = (const float*)d_in[5];
  const float* rec_b = (const float*)d_in[6];
  const float* dec_w = (const float*)d_in[7];
  const float* dec_b = (const float*)d_in[8];
  const float* hi_w  = (const float*)d_in[9];
  const float* hi_b  = (const float*)d_in[10];
  float* out = (float*)d_out;

  // workspace carve-out (~333 MB)
  char* ws = (char*)d_ws;
  size_t off = 0;
  auto carve = [&](size_t bytes)->char*{ char* p = ws + off; off += (bytes + 255) & ~(size_t)255; return p; };
  bf16_t* x_tm   = (bf16_t*)carve((size_t)Tt*Bb*Ii*2);   // 64 MB
  bf16_t* EH     = (bf16_t*)carve((size_t)Tt*Bb*Hh*2);   // 256 MB  enc -> h history
  bf16_t* h0b    = (bf16_t*)carve((size_t)Bb*Hh*2);
  bf16_t* enc_wb = (bf16_t*)carve((size_t)Hh*Ii*2);
  bf16_t* rec_wb = (bf16_t*)carve((size_t)Hh*Hh*2);
  bf16_t* dec_wb = (bf16_t*)carve((size_t)Oo*Hh*2);
  unsigned* flags = (unsigned*)carve(8*256*16*4);         // per-(blk,epi-wave) flags
  if (off > ws_size) return;  // diagnostic: leaves output zeroed

  // reset flags every call (ws is not re-poisoned between replays)
  hipMemsetAsync(flags, 0, 8*256*16*4, stream);

  // weights -> bf16
  k_f2b<<<(Hh*Ii)/1024, 256, 0, stream>>>(enc_wb, enc_w);
  k_f2b<<<(Hh*Hh)/1024, 256, 0, stream>>>(rec_wb, rec_w);
  k_f2b<<<(Oo*Hh)/1024, 256, 0, stream>>>(dec_wb, dec_w);
  k_init_h0<<<Hh/256, 256, 0, stream>>>(hi_w, hi_b, h0b);
  k_convert_x<<<((size_t)Tt*Bb*Ii/8)/256, 256, 0, stream>>>(x, x_tm);

  // encoder: EH[t*B+b, h] = x_tm @ enc_w^T + enc_b   (M=65536, K=512, N=2048)
  gemm128<0><<<dim3((Tt*Bb)/128, Hh/128), 256, 0, stream>>>(x_tm, Ii, enc_wb, Ii, enc_b, EH, Hh, Ii);

  // recurrence: one persistent cooperative kernel, 512 steps, 1024 threads/block
  {
    float* hfinal = out + (size_t)Tt*Bb*Oo;
    void* args[] = { (void*)&h0b, (void*)&rec_wb, (void*)&EH, (void*)&hfinal,
                     (void*)&rec_b, (void*)&hi_w, (void*)&hi_b, (void*)&dt, (void*)&a,
                     (void*)&flags };
    hipLaunchCooperativeKernel((const void*)rec_persist, dim3(REC_GRID), dim3(1024), args, 0, stream);
  }

  // decoder: out[t*B+b, o] = EH @ dec_w^T + dec_b   (M=65536, K=2048, N=512)
  gemm128<1><<<dim3((Tt*Bb)/128, Oo/128), 256, 0, stream>>>(EH, Hh, dec_wb, Hh, dec_b, out, Oo, Hh);
}

// Round 19
// 2398.429 us; speedup vs baseline: 1.7557x; 1.3735x over previous
//
#include <hip/hip_runtime.h>
#include <hip/hip_bf16.h>
#include <cmath>

// Problem dims
#define Bb 128
#define Tt 512
#define Ii 512
#define Hh 2048
#define Oo 512
#define REC_GRID 256

typedef __bf16 bf16_t;
typedef __bf16 bf16x8 __attribute__((ext_vector_type(8)));
typedef __bf16 bf16x4 __attribute__((ext_vector_type(4)));
typedef float  f32x4_t __attribute__((ext_vector_type(4)));
typedef unsigned u32;

static __device__ __forceinline__ bf16_t to_b(float v){ return (bf16_t)v; }
static __device__ __forceinline__ float  b2f(unsigned short u){ unsigned x = ((unsigned)u)<<16; return __builtin_bit_cast(float, x); }
static __device__ __forceinline__ unsigned short f2bbits(float v){ return __builtin_bit_cast(unsigned short, to_b(v)); }

// async global->LDS, 16B per lane: LDS dest = uniform base + lane*16, global
// source is PER-LANE (T21/m173) -- fragment-order landing via source scatter.
static __device__ __forceinline__ void gl_lds16(const void* g, void* l){
  __builtin_amdgcn_global_load_lds((const __attribute__((address_space(1))) void*)g,
                                   (__attribute__((address_space(3))) void*)l, 16, 0, 0);
}

#define REP4(M) M(0)M(1)M(2)M(3)

// ---------- small prep kernels ----------
__global__ __launch_bounds__(256) void k_f2b(bf16_t* __restrict__ dst, const float* __restrict__ src){
  size_t i = ((size_t)blockIdx.x*256 + threadIdx.x)*4;
  float4 v = *(const float4*)(src + i);
  bf16x4 o; o[0]=to_b(v.x); o[1]=to_b(v.y); o[2]=to_b(v.z); o[3]=to_b(v.w);
  *(bf16x4*)(dst + i) = o;
}

__global__ __launch_bounds__(256) void k_init_h0(const float* __restrict__ hi_w, const float* __restrict__ hi_b,
                                                 bf16_t* __restrict__ h0b){
  int i = blockIdx.x*256 + threadIdx.x;           // [0, H)
  bf16_t vb = to_b(hi_w[i] + hi_b[i]);
  for (int b=0;b<Bb;++b) h0b[(size_t)b*Hh + i] = vb;
}

__global__ __launch_bounds__(256) void k_convert_x(const float* __restrict__ x, bf16_t* __restrict__ x_tm){
  size_t idx = ((size_t)blockIdx.x*256 + threadIdx.x)*8;
  int    i0  = (int)(idx % Ii);
  size_t m   = idx / Ii;                          // m = t*B + b
  int    t   = (int)(m / Bb), b = (int)(m % Bb);
  const float* s = x + ((size_t)b*Tt + t)*Ii + i0;
  float4 v0 = *(const float4*)s, v1 = *(const float4*)(s+4);
  bf16x8 o;
  o[0]=to_b(v0.x); o[1]=to_b(v0.y); o[2]=to_b(v0.z); o[3]=to_b(v0.w);
  o[4]=to_b(v1.x); o[5]=to_b(v1.y); o[6]=to_b(v1.z); o[7]=to_b(v1.w);
  *(bf16x8*)(x_tm + idx) = o;
}

// ---------- GEMM building blocks (encoder / decoder) ----------
template<int ROWS, int KB>
static __device__ __forceinline__ void stage(const bf16_t* __restrict__ g, long ld, long row0, int k0,
                                             char* __restrict__ ldsT){
  constexpr int SLOTS = KB/8;
  constexpr int PT    = ROWS*SLOTS/256;
  #pragma unroll
  for (int j=0;j<PT;++j){
    int c    = threadIdx.x + 256*j;
    int row  = c / SLOTS, slot = c % SLOTS;
    uint4 v  = *(const uint4*)(g + (row0+row)*ld + k0 + slot*8);
    *(uint4*)(ldsT + row*(KB*2) + ((slot*16) ^ ((row&7)<<4))) = v;
  }
}

template<int KB>
static __device__ __forceinline__ bf16x8 frag(const char* __restrict__ ldsT, int row, int kk, int lane){
  int kbyte = kk*64 + ((lane>>4)<<4);
  return *(const bf16x8*)(ldsT + row*(KB*2) + (kbyte ^ ((row&7)<<4)));
}

template<int EPI>
__global__ __launch_bounds__(256) void gemm128(const bf16_t* __restrict__ A, long lda,
                                               const bf16_t* __restrict__ Bw, long ldb,
                                               const float* __restrict__ bias,
                                               void* __restrict__ Cout, long ldc, int K){
  constexpr int TM=128, TN=128, KB=64;
  __shared__ char lds[(TM+TN)*KB*2];
  char* ldsA = lds;
  char* ldsB = lds + TM*KB*2;
  long m0 = (long)blockIdx.x * TM;
  long n0 = (long)blockIdx.y * TN;
  int w = threadIdx.x >> 6, lane = threadIdx.x & 63;
  int wm = w >> 1, wn = w & 1;
  f32x4_t acc[4][4] = {};
  for (int k0=0;k0<K;k0+=KB){
    __syncthreads();
    stage<TM,KB>(A,  lda, m0, k0, ldsA);
    stage<TN,KB>(Bw, ldb, n0, k0, ldsB);
    __syncthreads();
    #pragma unroll
    for (int kk=0;kk<KB/32;++kk){
      bf16x8 af[4], bfv[4];
      #pragma unroll
      for (int f=0;f<4;++f){ int r = wm*64 + f*16 + (lane&15); af[f]  = frag<KB>(ldsA, r, kk, lane); }
      #pragma unroll
      for (int f=0;f<4;++f){ int r = wn*64 + f*16 + (lane&15); bfv[f] = frag<KB>(ldsB, r, kk, lane); }
      #pragma unroll
      for (int i=0;i<4;++i)
        #pragma unroll
        for (int j=0;j<4;++j)
          acc[i][j] = __builtin_amdgcn_mfma_f32_16x16x32_bf16(af[i], bfv[j], acc[i][j], 0,0,0);
    }
  }
  #pragma unroll
  for (int i=0;i<4;++i)
    #pragma unroll
    for (int j=0;j<4;++j)
      #pragma unroll
      for (int e=0;e<4;++e){
        long row = m0 + wm*64 + i*16 + ((lane>>4)<<2) + e;
        long col = n0 + wn*64 + j*16 + (lane&15);
        float v = acc[i][j][e] + bias[col];
        if (EPI==0) ((bf16_t*)Cout)[row*ldc + col] = to_b(v);
        else        ((float*) Cout)[row*ldc + col] = v;
      }
}

// ---------- persistent recurrence kernel (1024 threads / 16 waves) ----------
// 8 groups x 32 blocks (g=bid&7, XCD-local); group g owns batches 16g..+15;
// block (g,n) owns H-cols 64n..+63. Wave w = K-SIXTEENTH [w*128,+128):
// W slice = 4 col-groups x 4 kk = 16 named bf16x8 (64 VGPRs -- fits the
// 128-reg budget at 4 waves/SIMD, no remat pressure), loaded via the proven
// 2-pass fragment-order LDS alias. Volley chunks are wave-private (4 gl_lds,
// fragment-order source scatter, wave-local vmcnt -- R13-proven, no barrier).
// Poll: 2 producer blocks per wave. Reduction: scalar PLANES (lane-stride-4B,
// conflict-free both sides). Output: 1 element/thread (cg_o=w&3, e=w>>2).
// Epilogue: 65-padded f32 LDS exchange + cooperative u32 agent load/store.
__global__ __launch_bounds__(1024, 1) void rec_persist(
    const bf16_t* __restrict__ h0b, const bf16_t* __restrict__ W,
    bf16_t* __restrict__ EH, float* __restrict__ hfinal,
    const float* __restrict__ rec_b, const float* __restrict__ hi_w, const float* __restrict__ hi_b,
    const float* __restrict__ dtp, const float* __restrict__ ap,
    unsigned* __restrict__ flags)
{
  __shared__ char lds[65536 + 65536 + 4352];   // hbuf + redf + xbf (init aliases first 128K)
  char*  hbuf = lds;                           // 64 KB volley (64 chunks x 1KB)
  float* redf = (float*)(lds + 65536);         // 64 KB: 256 planes x 64 lanes
  float* xbf  = (float*)(lds + 131072);        // 16 x 65 padded exchange

  const int bid = blockIdx.x;
  const int g   = bid & 7;               // batch group == XCD (locality heuristic)
  const int n   = bid >> 3;              // H tile 0..31
  const int m0  = g * 16;
  const int n0  = n * 64;
  unsigned* gflags = flags + g*32*16;    // 32 flags, 64B stride
  const int tid = threadIdx.x, w = tid >> 6, lane = tid & 63;
  const int l15 = lane & 15, w4 = w*4;

  // ---- one-time: W -> 16 named VGPR frags via 2 fragment-order LDS passes ----
  #define WDCL(i) bf16x8 wa##i, wb##i, wc##i, wd##i;
  REP4(WDCL)
  #undef WDCL
  #pragma unroll 1
  for (int p = 0; p < 2; ++p){
    __syncthreads();
    for (int it = 0; it < 8; ++it){
      int cid = it*1024 + tid;           // 8192 chunks of 16B = 128KB
      int lc  = cid & 63, kk = (cid >> 6) & 63, cgl = cid >> 12;
      uint4 v = *(const uint4*)(W + (size_t)(n0 + p*32 + cgl*16 + (lc&15))*Hh + kk*32 + ((lc>>4)<<3));
      *(uint4*)(lds + (size_t)cid*16) = v;
    }
    __syncthreads();
    if (p == 0){
      #define WRD(i) \
        wa##i = *(const bf16x8*)(lds + (size_t)((     w4 + (i))*64 + lane)*16); \
        wb##i = *(const bf16x8*)(lds + (size_t)((64 + w4 + (i))*64 + lane)*16);
      REP4(WRD)
      #undef WRD
    } else {
      #define WRD(i) \
        wc##i = *(const bf16x8*)(lds + (size_t)((     w4 + (i))*64 + lane)*16); \
        wd##i = *(const bf16x8*)(lds + (size_t)((64 + w4 + (i))*64 + lane)*16);
      REP4(WRD)
      #undef WRD
    }
  }
  __syncthreads();                       // all W reads done; LDS reusable

  const float s  = 1.f/(1.f + __expf(-dtp[0]));
  const float av = ap[0];
  // output role: 1 element per thread
  const int   cg_o = w & 3, eo = w >> 2;
  const int   batch = m0 + l15;
  const int   col_l = cg_o*16 + ((lane >> 4) << 2) + eo;
  const int   hcol  = n0 + col_l;
  const int   pos   = l15*65 + col_l;    // padded xbf slot
  const float rbv = rec_b[hcol];
  float hm = hi_w[hcol] + hi_b[hcol];

  // volley source (per-lane scatter, fragment order; R12-proven)
  const size_t vsrc_off = (size_t)(m0 + l15)*Hh + ((lane>>4)<<3);
  // cooperative enc/h slot (tid<512): batch tid>>5, col pair tid&31
  const int co_b = m0 + (tid >> 5);
  const int co_c = n0 + (tid & 31)*2;
  // this wave's 2 producer-block flags (cols w*128..+128 come from n'=2w,2w+1)
  const unsigned* fp = gflags + (w*2 + (lane & 1))*16;

  for (int t = 0; t < Tt; ++t){
    const bf16_t* Asrc = (t==0) ? h0b : (EH + (size_t)(t-1)*(Bb*Hh));
    bf16_t* EHt = EH + (size_t)t*(Bb*Hh);

    // enc load first (same-block data, no producer hazard) -- hides under poll
    u32 ecv = 0;
    if (tid < 512)
      ecv = __hip_atomic_load((const u32*)(EHt + (size_t)co_b*Hh + co_c),
                              __ATOMIC_RELAXED, __HIP_MEMORY_SCOPE_AGENT);

    // wave-local wait: only this wave's 2 producers must have finished t-1
    if (t){
      unsigned tt = (unsigned)t;
      for (;;){
        unsigned v = __hip_atomic_load(fp, __ATOMIC_RELAXED, __HIP_MEMORY_SCOPE_AGENT);
        if (__all((int)(v >= tt))) break;
        __builtin_amdgcn_s_sleep(2);
      }
    }

    // wave-private volley: stage + read only chunks w*4..w*4+3
    {
      const bf16_t* src = Asrc + vsrc_off;
      #pragma unroll
      for (int i = 0; i < 4; ++i)
        gl_lds16(src + (w4 + i)*32, hbuf + (size_t)(w4 + i)*1024);
    }
    asm volatile("s_waitcnt vmcnt(0)" ::: "memory");   // volley + ecv complete (this wave)

    // K-loop: 4 conflict-free h ds_reads, 16 MFMAs (4 col-groups x 4 kk)
    f32x4_t acc0 = {0.f,0.f,0.f,0.f}, acc1 = acc0, acc2 = acc0, acc3 = acc0;
    #define KS(i) { \
      bf16x8 hv = *(const bf16x8*)(hbuf + (size_t)(w4 + (i))*1024 + (size_t)lane*16); \
      acc0 = __builtin_amdgcn_mfma_f32_16x16x32_bf16(wa##i, hv, acc0, 0,0,0); \
      acc1 = __builtin_amdgcn_mfma_f32_16x16x32_bf16(wb##i, hv, acc1, 0,0,0); \
      acc2 = __builtin_amdgcn_mfma_f32_16x16x32_bf16(wc##i, hv, acc2, 0,0,0); \
      acc3 = __builtin_amdgcn_mfma_f32_16x16x32_bf16(wd##i, hv, acc3, 0,0,0); }
    REP4(KS)
    #undef KS

    // K-reduction via scalar planes: write lane-stride-4B (conflict-free)
    #pragma unroll
    for (int e=0;e<4;++e){
      redf[(w*16 +  0 + e)*64 + lane] = acc0[e];
      redf[(w*16 +  4 + e)*64 + lane] = acc1[e];
      redf[(w*16 +  8 + e)*64 + lane] = acc2[e];
      redf[(w*16 + 12 + e)*64 + lane] = acc3[e];
    }
    if (tid < 512){
      xbf[(tid>>5)*65 + (tid&31)*2    ] = b2f((unsigned short)(ecv & 0xffffu));
      xbf[(tid>>5)*65 + (tid&31)*2 + 1] = b2f((unsigned short)(ecv >> 16));
    }
    __syncthreads();                     // B: red planes + enc exchange visible

    float fa = 0.f;
    #pragma unroll
    for (int q=0;q<16;++q) fa += redf[(q*16 + cg_o*4 + eo)*64 + lane];

    // gated tanh update (1 element/thread); same-thread read-then-write on xbf[pos]
    {
      float enc = xbf[pos];
      float pre = enc + av*(fa + rbv);
      float th  = 1.f - 2.f/(__expf(2.f*pre) + 1.f);   // tanh
      hm = (1.f - s)*hm + s*th;
      xbf[pos] = hm;
    }
    __syncthreads();                     // C: h values in exchange

    if (tid < 512){
      float h0f = xbf[(tid>>5)*65 + (tid&31)*2];
      float h1f = xbf[(tid>>5)*65 + (tid&31)*2 + 1];
      u32 ov = (u32)f2bbits(h0f) | ((u32)f2bbits(h1f) << 16);
      __hip_atomic_store((u32*)(EHt + (size_t)co_b*Hh + co_c), ov,
                         __ATOMIC_RELAXED, __HIP_MEMORY_SCOPE_AGENT);
    }
    __syncthreads();                     // D: all waves' stores drained (vmcnt0/wave)
    if (tid == 0)
      __hip_atomic_store(gflags + n*16, (unsigned)(t+1),
                         __ATOMIC_RELAXED, __HIP_MEMORY_SCOPE_AGENT);
  }

  // final hidden (f32) -> out tail
  hfinal[(size_t)batch*Hh + hcol] = hm;
}

// ---------- launch ----------
extern "C" void kernel_launch(void* const* d_in, const int* in_sizes, int n_in,
                              void* d_out, int out_size, void* d_ws, size_t ws_size,
                              hipStream_t stream){
  const float* x     = (const float*)d_in[0];
  const float* dt    = (const float*)d_in[1];
  const float* a     = (const float*)d_in[2];
  const float* enc_w = (const float*)d_in[3];
  const float* enc_b = (const float*)d_in[4];
  const float* rec_w = (const float*)d_in[5];
  const float* rec_b = (const float*)d_in[6];
  const float* dec_w = (const float*)d_in[7];
  const float* dec_b = (const float*)d_in[8];
  const float* hi_w  = (const float*)d_in[9];
  const float* hi_b  = (const float*)d_in[10];
  float* out = (float*)d_out;

  // workspace carve-out (~333 MB)
  char* ws = (char*)d_ws;
  size_t off = 0;
  auto carve = [&](size_t bytes)->char*{ char* p = ws + off; off += (bytes + 255) & ~(size_t)255; return p; };
  bf16_t* x_tm   = (bf16_t*)carve((size_t)Tt*Bb*Ii*2);   // 64 MB
  bf16_t* EH     = (bf16_t*)carve((size_t)Tt*Bb*Hh*2);   // 256 MB  enc -> h history
  bf16_t* h0b    = (bf16_t*)carve((size_t)Bb*Hh*2);
  bf16_t* enc_wb = (bf16_t*)carve((size_t)Hh*Ii*2);
  bf16_t* rec_wb = (bf16_t*)carve((size_t)Hh*Hh*2);
  bf16_t* dec_wb = (bf16_t*)carve((size_t)Oo*Hh*2);
  unsigned* flags = (unsigned*)carve(8*32*16*4);          // per-block flags, 64B stride
  if (off > ws_size) return;  // diagnostic: leaves output zeroed

  // reset flags every call (ws is not re-poisoned between replays)
  hipMemsetAsync(flags, 0, 8*32*16*4, stream);

  // weights -> bf16
  k_f2b<<<(Hh*Ii)/1024, 256, 0, stream>>>(enc_wb, enc_w);
  k_f2b<<<(Hh*Hh)/1024, 256, 0, stream>>>(rec_wb, rec_w);
  k_f2b<<<(Oo*Hh)/1024, 256, 0, stream>>>(dec_wb, dec_w);
  k_init_h0<<<Hh/256, 256, 0, stream>>>(hi_w, hi_b, h0b);
  k_convert_x<<<((size_t)Tt*Bb*Ii/8)/256, 256, 0, stream>>>(x, x_tm);

  // encoder: EH[t*B+b, h] = x_tm @ enc_w^T + enc_b   (M=65536, K=512, N=2048)
  gemm128<0><<<dim3((Tt*Bb)/128, Hh/128), 256, 0, stream>>>(x_tm, Ii, enc_wb, Ii, enc_b, EH, Hh, Ii);

  // recurrence: one persistent cooperative kernel, 512 steps, 1024 threads/block
  {
    float* hfinal = out + (size_t)Tt*Bb*Oo;
    void* args[] = { (void*)&h0b, (void*)&rec_wb, (void*)&EH, (void*)&hfinal,
                     (void*)&rec_b, (void*)&hi_w, (void*)&hi_b, (void*)&dt, (void*)&a,
                     (void*)&flags };
    hipLaunchCooperativeKernel((const void*)rec_persist, dim3(REC_GRID), dim3(1024), args, 0, stream);
  }

  // decoder: out[t*B+b, o] = EH @ dec_w^T + dec_b   (M=65536, K=2048, N=512)
  gemm128<1><<<dim3((Tt*Bb)/128, Oo/128), 256, 0, stream>>>(EH, Hh, dec_wb, Hh, dec_b, out, Oo, Hh);
}